// Round 1
// baseline (117.294 us; speedup 1.0000x reference)
//
#include <hip/hip_runtime.h>
#include <hip/hip_bf16.h>

typedef __bf16 bf16;
typedef __attribute__((ext_vector_type(4))) __bf16 bf16x4;
typedef __attribute__((ext_vector_type(8))) __bf16 bf16x8;
typedef __attribute__((ext_vector_type(4))) float f32x4;

#define SEQ   4096
#define DIMN  1024
#define NHEAD 8
#define HD    128
#define MALL  4160   /* 4096 X rows + 64 Cp rows */
#define PENV  -10000.0f

// ---------------------------------------------------------------- cvt: fp32 -> bf16, X ++ Cp
__global__ __launch_bounds__(256) void cvt_cat_kernel(
    const float* __restrict__ X, const float* __restrict__ Cp, bf16* __restrict__ A) {
  int i = blockIdx.x * 256 + threadIdx.x;
  size_t base = (size_t)i * 4;
  if (base >= (size_t)MALL * DIMN) return;
  const float* src = (base < (size_t)SEQ * DIMN) ? (X + base) : (Cp + (base - (size_t)SEQ * DIMN));
  float4 v = *(const float4*)src;
  bf16x4 o;
  o[0] = (bf16)v.x; o[1] = (bf16)v.y; o[2] = (bf16)v.z; o[3] = (bf16)v.w;
  *(bf16x4*)&A[base] = o;
}

// ---------------------------------------------------------------- cvt+transpose W[k][n] -> Wt[n][k] bf16
__global__ __launch_bounds__(256) void cvt_trans_kernel(
    const float* __restrict__ W0, const float* __restrict__ W1, const float* __restrict__ W2,
    bf16* __restrict__ Wt) {
  const float* W = (blockIdx.z == 0) ? W0 : ((blockIdx.z == 1) ? W1 : W2);
  bf16* dst = Wt + (size_t)blockIdx.z * DIMN * DIMN;
  __shared__ bf16 tile[64][72];
  int k0 = blockIdx.y * 64, n0 = blockIdx.x * 64;
  int tx = threadIdx.x & 63, ty = threadIdx.x >> 6;
#pragma unroll
  for (int r = ty; r < 64; r += 4)
    tile[tx][r] = (bf16)W[(size_t)(k0 + r) * DIMN + n0 + tx];
  __syncthreads();
#pragma unroll
  for (int r = ty; r < 64; r += 4)
    dst[(size_t)(n0 + r) * DIMN + k0 + tx] = tile[r][tx];
}

// ---------------------------------------------------------------- fused QKV GEMM: out = A @ W^T(stored [n][k]) + b
// z = 0:Q (M=4096), 1:K (M=4160), 2:V (M=4160). 128x128 tile, 4 waves, 16x16x32 bf16 MFMA.
__global__ __launch_bounds__(256) void gemm_qkv_kernel(
    const bf16* __restrict__ A, const bf16* __restrict__ Wt,
    const float* __restrict__ bQ, const float* __restrict__ bK, const float* __restrict__ bV,
    bf16* __restrict__ QKV) {
  const int z = blockIdx.z;
  const int M = (z == 0) ? SEQ : MALL;
  const int m0 = blockIdx.y * 128;
  if (m0 >= M) return;
  const int n0 = blockIdx.x * 128;
  const bf16* Wz = Wt + (size_t)z * DIMN * DIMN;
  const float* bias = (z == 0) ? bQ : ((z == 1) ? bK : bV);
  bf16* out = QKV + (size_t)z * MALL * DIMN;

  __shared__ bf16 As[128][72];
  __shared__ bf16 Bs[128][72];
  const int t = threadIdx.x;
  const int lane = t & 63, w = t >> 6;
  const int wr = w >> 1, wc = w & 1;
  const int r16 = lane & 15, g4 = lane >> 4;
  f32x4 acc[4][4] = {};

  for (int kt = 0; kt < 16; ++kt) {
    __syncthreads();
#pragma unroll
    for (int i = 0; i < 4; ++i) {
      int idx = i * 256 + t;
      int row = idx >> 3, kc = idx & 7;
      int gm = m0 + row; gm = (gm < M) ? gm : (M - 1);
      *(bf16x8*)&As[row][kc * 8] = *(const bf16x8*)&A[(size_t)gm * DIMN + kt * 64 + kc * 8];
      *(bf16x8*)&Bs[row][kc * 8] = *(const bf16x8*)&Wz[(size_t)(n0 + row) * DIMN + kt * 64 + kc * 8];
    }
    __syncthreads();
#pragma unroll
    for (int kk = 0; kk < 2; ++kk) {
      bf16x8 af[4], bfr[4];
#pragma unroll
      for (int mi = 0; mi < 4; ++mi)
        af[mi] = *(const bf16x8*)&As[wr * 64 + mi * 16 + r16][kk * 32 + g4 * 8];
#pragma unroll
      for (int nj = 0; nj < 4; ++nj)
        bfr[nj] = *(const bf16x8*)&Bs[wc * 64 + nj * 16 + r16][kk * 32 + g4 * 8];
#pragma unroll
      for (int mi = 0; mi < 4; ++mi)
#pragma unroll
        for (int nj = 0; nj < 4; ++nj)
          acc[mi][nj] = __builtin_amdgcn_mfma_f32_16x16x32_bf16(af[mi], bfr[nj], acc[mi][nj], 0, 0, 0);
    }
  }
#pragma unroll
  for (int nj = 0; nj < 4; ++nj) {
    int n = n0 + wc * 64 + nj * 16 + r16;
    float bv = bias[n];
#pragma unroll
    for (int mi = 0; mi < 4; ++mi) {
      int mbase = m0 + wr * 64 + mi * 16 + g4 * 4;
#pragma unroll
      for (int r = 0; r < 4; ++r) {
        int m = mbase + r;
        if (m < M) out[(size_t)m * DIMN + n] = (bf16)(acc[mi][nj][r] + bv);
      }
    }
  }
}

// ---------------------------------------------------------------- key slot -> global row map (band paths)
__device__ __forceinline__ int key_row_map(int qb, int tslot) {
  if (qb <= 1) return tslot;                                    // rows 0..255
  if (qb == 63) return (tslot < 64) ? tslot : (3840 + tslot);   // block0 then blocks 61..63
  return (tslot < 64) ? tslot : ((qb - 1) * 64 + (tslot - 64)); // block0 + 3-block window
}

// ---------------------------------------------------------------- fused attention
// grid (64 qblocks, 8 heads), 256 threads (4 waves x 16 queries each).
__global__ __launch_bounds__(256) void attn_kernel(
    const bf16* __restrict__ Q, const bf16* __restrict__ K, const bf16* __restrict__ V,
    const float* __restrict__ mask, float* __restrict__ out) {
  const int qb = blockIdx.x, h = blockIdx.y;
  const int t = threadIdx.x;
  const int lane = t & 63, w = t >> 6;
  const int c16 = lane & 15, g4 = lane >> 4;
  const float sl = exp2f(-(float)(h + 1));
  const float rsq = 0.088388347648318447f;  // 1/sqrt(128)

  __shared__ bf16 KV[9216];      // union: K tile [64][136] (8704) | V^T tile [128][72] (9216)
  __shared__ bf16 P[64][264];    // probabilities, bf16, padded

  // --- Q fragments straight from global (each wave's own 16 query rows)
  bf16x8 qf[4];
  {
    int srow = qb * 64 + w * 16 + c16;
    const bf16* qp = Q + (size_t)srow * DIMN + h * HD + g4 * 8;
#pragma unroll
    for (int ks = 0; ks < 4; ++ks) qf[ks] = *(const bf16x8*)(qp + ks * 32);
  }

  int iq[4]; float mi[4];
#pragma unroll
  for (int r = 0; r < 4; ++r) { iq[r] = qb * 64 + w * 16 + g4 * 4 + r; mi[r] = mask[iq[r]]; }

  // --- band scores: 4 chunks x 64 keys
  f32x4 sc[16] = {};
#pragma unroll
  for (int c = 0; c < 4; ++c) {
    __syncthreads();
#pragma unroll
    for (int i = 0; i < 4; ++i) {
      int idx = i * 256 + t;
      int kr = idx >> 4, dc = idx & 15;
      int gr = key_row_map(qb, c * 64 + kr);
      *(bf16x8*)&KV[kr * 136 + dc * 8] = *(const bf16x8*)&K[(size_t)gr * DIMN + h * HD + dc * 8];
    }
    __syncthreads();
#pragma unroll
    for (int ks = 0; ks < 4; ++ks)
#pragma unroll
      for (int kj = 0; kj < 4; ++kj) {
        bf16x8 bfr = *(const bf16x8*)&KV[(kj * 16 + c16) * 136 + ks * 32 + g4 * 8];
        sc[c * 4 + kj] = __builtin_amdgcn_mfma_f32_16x16x32_bf16(qf[ks], bfr, sc[c * 4 + kj], 0, 0, 0);
      }
  }

  // --- bias (distance + mask penalties) — replicates reference quirks exactly
#pragma unroll
  for (int f = 0; f < 16; ++f) {
    int tslot = f * 16 + c16;
    int jrow = key_row_map(qb, tslot);
    float mj = mask[jrow];
    int jpos = (qb == 63) ? (3840 + tslot) : jrow;   // last block: virtual key positions
    int ishift = (qb >= 2 && qb <= 62) ? 128 : 0;    // middle band: row counter from 0 quirk
#pragma unroll
    for (int r = 0; r < 4; ++r) {
      float raw = sc[f][r];
      float dist = sl * fabsf((float)(iq[r] - ishift - jpos));
      float s;
      if (qb <= 1)       s = raw * rsq - dist + (1.f - mi[r]) * PENV;
      else if (qb == 63) s = raw * rsq - dist;
      else {
        float pen = (tslot < 64) ? (1.f - mi[r]) * PENV : (1.f - mi[r] * mj) * PENV;
        s = (raw + pen) * rsq - dist;
      }
      sc[f][r] = s;
    }
  }

  // --- in-wave softmax over 256 keys (per query row), normalize, P -> LDS
  {
#pragma unroll
    for (int r = 0; r < 4; ++r) {
      float m = -1e30f;
#pragma unroll
      for (int f = 0; f < 16; ++f) m = fmaxf(m, sc[f][r]);
#pragma unroll
      for (int d = 1; d < 16; d <<= 1) m = fmaxf(m, __shfl_xor(m, d));
      float s = 0.f;
#pragma unroll
      for (int f = 0; f < 16; ++f) { float e = __expf(sc[f][r] - m); sc[f][r] = e; s += e; }
#pragma unroll
      for (int d = 1; d < 16; d <<= 1) s += __shfl_xor(s, d);
      float inv = 1.0f / s;
#pragma unroll
      for (int f = 0; f < 16; ++f)
        P[w * 16 + g4 * 4 + r][f * 16 + c16] = (bf16)(sc[f][r] * inv);
    }
  }

  // --- band PV: 4 chunks, V staged transposed
  f32x4 ctx[8] = {};
#pragma unroll
  for (int c = 0; c < 4; ++c) {
    __syncthreads();  // all waves done with KV (scores) / previous chunk
#pragma unroll
    for (int i = 0; i < 4; ++i) {
      int idx = i * 256 + t;
      int vr = idx >> 4, dc = idx & 15;
      int gr = key_row_map(qb, c * 64 + vr);
      bf16x8 vv = *(const bf16x8*)&V[(size_t)gr * DIMN + h * HD + dc * 8];
#pragma unroll
      for (int j = 0; j < 8; ++j) KV[(dc * 8 + j) * 72 + vr] = vv[j];
    }
    __syncthreads();
#pragma unroll
    for (int ks = 0; ks < 2; ++ks) {
      bf16x8 pa = *(const bf16x8*)&P[w * 16 + c16][c * 64 + ks * 32 + g4 * 8];
#pragma unroll
      for (int df = 0; df < 8; ++df) {
        bf16x8 bv = *(const bf16x8*)&KV[(df * 16 + c16) * 72 + ks * 32 + g4 * 8];
        ctx[df] = __builtin_amdgcn_mfma_f32_16x16x32_bf16(pa, bv, ctx[df], 0, 0, 0);
      }
    }
  }

  // --- packed path (64 Cp keys, separate softmax; constants cancel so score = raw*rsq)
  __syncthreads();
#pragma unroll
  for (int i = 0; i < 4; ++i) {
    int idx = i * 256 + t;
    int kr = idx >> 4, dc = idx & 15;
    *(bf16x8*)&KV[kr * 136 + dc * 8] = *(const bf16x8*)&K[(size_t)(SEQ + kr) * DIMN + h * HD + dc * 8];
  }
  __syncthreads();
  f32x4 sp[4] = {};
#pragma unroll
  for (int ks = 0; ks < 4; ++ks)
#pragma unroll
    for (int kj = 0; kj < 4; ++kj) {
      bf16x8 bfr = *(const bf16x8*)&KV[(kj * 16 + c16) * 136 + ks * 32 + g4 * 8];
      sp[kj] = __builtin_amdgcn_mfma_f32_16x16x32_bf16(qf[ks], bfr, sp[kj], 0, 0, 0);
    }
#pragma unroll
  for (int r = 0; r < 4; ++r) {
    float m = -1e30f;
#pragma unroll
    for (int kj = 0; kj < 4; ++kj) m = fmaxf(m, sp[kj][r] * rsq);
#pragma unroll
    for (int d = 1; d < 16; d <<= 1) m = fmaxf(m, __shfl_xor(m, d));
    float s = 0.f;
    float e[4];
#pragma unroll
    for (int kj = 0; kj < 4; ++kj) { e[kj] = __expf(sp[kj][r] * rsq - m); s += e[kj]; }
#pragma unroll
    for (int d = 1; d < 16; d <<= 1) s += __shfl_xor(s, d);
    float inv = mi[r] / s;  // packed context is pre-scaled by mask_v
#pragma unroll
    for (int kj = 0; kj < 4; ++kj)
      P[w * 16 + g4 * 4 + r][kj * 16 + c16] = (bf16)(e[kj] * inv);
  }
  __syncthreads();  // all waves done reading KV (packed scores) before V^T restage
#pragma unroll
  for (int i = 0; i < 4; ++i) {
    int idx = i * 256 + t;
    int vr = idx >> 4, dc = idx & 15;
    bf16x8 vv = *(const bf16x8*)&V[(size_t)(SEQ + vr) * DIMN + h * HD + dc * 8];
#pragma unroll
    for (int j = 0; j < 8; ++j) KV[(dc * 8 + j) * 72 + vr] = vv[j];
  }
  __syncthreads();
#pragma unroll
  for (int ks = 0; ks < 2; ++ks) {
    bf16x8 pa = *(const bf16x8*)&P[w * 16 + c16][ks * 32 + g4 * 8];
#pragma unroll
    for (int df = 0; df < 8; ++df) {
      bf16x8 bv = *(const bf16x8*)&KV[(df * 16 + c16) * 72 + ks * 32 + g4 * 8];
      ctx[df] = __builtin_amdgcn_mfma_f32_16x16x32_bf16(pa, bv, ctx[df], 0, 0, 0);
    }
  }

  // --- output: raw [H,S,hd] flatten; final mask uses the reshaped row quirk mask[h*512 + s/8]
#pragma unroll
  for (int df = 0; df < 8; ++df) {
    int d = df * 16 + c16;
#pragma unroll
    for (int r = 0; r < 4; ++r) {
      int s = iq[r];
      float fm = mask[h * 512 + (s >> 3)];
      out[(size_t)h * (SEQ * HD) + (size_t)s * HD + d] = ctx[df][r] * fm;
    }
  }
}

// ---------------------------------------------------------------- launch
extern "C" void kernel_launch(void* const* d_in, const int* in_sizes, int n_in,
                              void* d_out, int out_size, void* d_ws, size_t ws_size,
                              hipStream_t stream) {
  const float* X    = (const float*)d_in[0];
  const float* Cp   = (const float*)d_in[1];
  const float* mask = (const float*)d_in[2];
  const float* WQ   = (const float*)d_in[3];
  const float* bQ   = (const float*)d_in[4];
  const float* WK   = (const float*)d_in[5];
  const float* bK   = (const float*)d_in[6];
  const float* WV   = (const float*)d_in[7];
  const float* bV   = (const float*)d_in[8];
  float* out = (float*)d_out;

  bf16* Abf = (bf16*)d_ws;                              // [4160][1024]
  bf16* Wt  = Abf + (size_t)MALL * DIMN;                // 3 x [1024][1024] (transposed)
  bf16* QKV = Wt + (size_t)3 * DIMN * DIMN;             // 3 x [4160][1024]: q, k, v

  int nCvt = (MALL * DIMN / 4 + 255) / 256;
  cvt_cat_kernel<<<nCvt, 256, 0, stream>>>(X, Cp, Abf);
  cvt_trans_kernel<<<dim3(16, 16, 3), 256, 0, stream>>>(WQ, WK, WV, Wt);
  gemm_qkv_kernel<<<dim3(8, 33, 3), 256, 0, stream>>>(Abf, Wt, bQ, bK, bV, QKV);
  attn_kernel<<<dim3(64, 8), 256, 0, stream>>>(QKV, QKV + (size_t)MALL * DIMN,
                                               QKV + (size_t)2 * MALL * DIMN, mask, out);
}